// Round 11
// baseline (381.350 us; speedup 1.0000x reference)
//
#include <hip/hip_runtime.h>

#define GAT_N 50000
#define GAT_D 256
#define GAT_T 3
#define GAT_E 250000
#define GAT_B (GAT_T*GAT_N)      // 150000 (node,type) buckets
#define GAT_TOTE (GAT_T*GAT_E)   // 750000 edges total
#define GAT_COLS (GAT_T*GAT_D)   // 768 fused output columns
#define GAT_SLOPE 0.2f

typedef unsigned short u16;
typedef unsigned int u32;
typedef __attribute__((ext_vector_type(8))) short s16x8;     // raw bf16 storage
typedef __attribute__((ext_vector_type(8))) __bf16 bf16x8;   // MFMA operand
typedef __attribute__((ext_vector_type(4))) float f32x4;
typedef __attribute__((ext_vector_type(2))) u32 u32x2;

__device__ __forceinline__ u16 f2bf(float f) {
    u32 x = __builtin_bit_cast(u32, f);
    u32 r = (x + 0x7fffu + ((x >> 16) & 1u)) >> 16;   // RNE
    return (u16)r;
}
__device__ __forceinline__ float lo16(u32 w) {
    return __builtin_bit_cast(float, w << 16);
}
__device__ __forceinline__ float hi16(u32 w) {
    return __builtin_bit_cast(float, w & 0xffff0000u);
}

// ---- DPP butterfly adds (VALU pipe, NOT ds_swizzle/LDS pipe) --------------
template<int CTRL>
__device__ __forceinline__ float dppadd(float x) {
    int y = __builtin_amdgcn_update_dpp(0, __builtin_bit_cast(int, x),
                                        CTRL, 0xf, 0xf, true);
    return x + __builtin_bit_cast(float, y);
}
__device__ __forceinline__ float sum16(float x) {   // reduce within 16 lanes
    x = dppadd<0xB1>(x);
    x = dppadd<0x4E>(x);
    x = dppadd<0x141>(x);
    x = dppadd<0x140>(x);
    return x;
}

// ---- r11: fused prep + scatter (1 dispatch; independent work) -------------
// prep: W1/W2 -> bf16 transposed (coalesced OUT index), z -> bf16, bias3.
// scatter: fixed 64-slot slab per dst (r10), atomicAdd(&deg[dst]).
// deg zeroed by the up-front memset (same stream, ordered).
__global__ void gat_prep(const float* __restrict__ W1, const float* __restrict__ W2,
                         const float* __restrict__ z, const float* __restrict__ b1,
                         const float* __restrict__ b2, const int* __restrict__ ei,
                         u16* __restrict__ WT1b, u16* __restrict__ WT2b,
                         u16* __restrict__ zb, u32* __restrict__ deg,
                         int* __restrict__ psrc2, float* __restrict__ bias3)
{
    int idx = blockIdx.x * 256 + threadIdx.x;
    if (idx < GAT_T * GAT_D * GAT_D) {               // 196608 OUTPUT slots
        int t = idx >> 16, r = idx & 65535;
        int h = r >> 8, d = r & 255;                 // out = [t][h][d]
        WT1b[idx] = f2bf(W1[t * 65536 + d * 256 + h]);
        WT2b[idx] = f2bf(W2[t * 65536 + d * 256 + h]);
    }
    if (idx < 2 * GAT_D) {
        const float* bb = (idx < GAT_D) ? b1 : b2;
        int c = idx & 255;
        bias3[idx] = bb[c] + bb[GAT_D + c] + bb[2 * GAT_D + c];
    }
    if (idx < GAT_TOTE) {                            // fused scatter
        int t = idx / GAT_E;
        int e = idx - t * GAT_E;
        int src = ei[t * 2 * GAT_E + e];
        int dst = ei[t * 2 * GAT_E + GAT_E + e];
        u32 slot = atomicAdd(&deg[dst], 1u);
        if (slot < 64u)                              // safety clamp
            psrc2[(size_t)dst * 64 + slot] = t * GAT_N + src;
    }
    if (idx < GAT_N * GAT_D / 4) {
        f32x4 v = ((const f32x4*)z)[idx];
        ushort4 pk;
        pk.x = f2bf(v.x); pk.y = f2bf(v.y); pk.z = f2bf(v.z); pk.w = f2bf(v.w);
        ((ushort4*)zb)[idx] = pk;
    }
}

// ================= LDS-staged MFMA GEMM (XOR-swizzled) + fused attn dots ====
// r7 compute path (128x128 tile, 512-thread/8-wave blocks, 64 KB dbuf LDS,
// counted vmcnt, XCD grid swizzle, DPP epilogue reduction).
// r11: epilogue-2 accumulates DIRECTLY into the per-layer a_src/a_dst via
// atomicAdd (each address hit exactly 8x total -> negligible contention;
// fp32 atomic ordering variance << 2^-8 tolerance). Deletes gat_sum x2.
__global__ __launch_bounds__(512, 4) void gat_gemm(
    const u16* __restrict__ A, const u16* __restrict__ WTb,
    u16* __restrict__ H, const float* __restrict__ as_in,
    const float* __restrict__ ad_in, float* __restrict__ a_s,
    float* __restrict__ a_d)
{
    // decode XCD-grouped swizzle
    int lin = blockIdx.x;
    int g   = lin / 48;
    int rem = lin - g * 48;
    int bc  = rem >> 3;                 // col tile 0..5
    int br  = (g << 3) + (rem & 7);     // row slab 0..390
    if (br >= 391) return;

    __shared__ u16 Als[2][128 * 64];   // 2 x 16 KB
    __shared__ u16 Bls[2][128 * 64];   // 2 x 16 KB
    int tid  = threadIdx.x;
    int wave = tid >> 6, lane = tid & 63;
    int quad = lane >> 4, l16 = lane & 15;
    int wm = wave & 1, wn = wave >> 1;       // wm: row half, wn: col quarter
    int lrow = lane >> 3;                    // 0..7
    int swz  = ((lane & 7) ^ lrow) * 8;      // swizzled k-offset (u16)

    size_t arow0 = (size_t)br * 128;
    size_t brow0 = (size_t)bc * 128;

    auto STAGE = [&](int buf, int ks) {
        int k0 = ks * 64;
        #pragma unroll
        for (int r = 0; r < 2; ++r) {
            int srow = wave * 16 + r * 8 + lrow;
            const u16* gA = A   + (arow0 + srow) * GAT_D + k0 + swz;
            const u16* gB = WTb + (brow0 + srow) * GAT_D + k0 + swz;
            u16* lA = &Als[buf][wave * 1024 + r * 512];   // wave-uniform dest
            u16* lB = &Bls[buf][wave * 1024 + r * 512];
#if defined(__has_builtin) && __has_builtin(__builtin_amdgcn_global_load_lds)
            __builtin_amdgcn_global_load_lds(
                (const __attribute__((address_space(1))) void*)gA,
                (__attribute__((address_space(3))) void*)lA, 16, 0, 0);
            __builtin_amdgcn_global_load_lds(
                (const __attribute__((address_space(1))) void*)gB,
                (__attribute__((address_space(3))) void*)lB, 16, 0, 0);
#else
            *(s16x8*)(lA + lane * 8) = *(const s16x8*)gA;
            *(s16x8*)(lB + lane * 8) = *(const s16x8*)gB;
#endif
        }
    };

    f32x4 acc[4][2] = {};

    STAGE(0, 0);
    #pragma unroll
    for (int ks = 0; ks < 4; ++ks) {
        int cur = ks & 1;
        if (ks < 3) {
            STAGE(cur ^ 1, ks + 1);
            asm volatile("s_waitcnt vmcnt(4)" ::: "memory");
        } else {
            asm volatile("s_waitcnt vmcnt(0)" ::: "memory");
        }
        __builtin_amdgcn_s_barrier();     // all waves' stage of cur complete

        #pragma unroll
        for (int kk = 0; kk < 2; ++kk) {
            int csw8 = ((kk * 4 + quad) ^ (l16 & 7)) * 8;   // row&7 == l16&7
            bf16x8 af[4], bf[2];
            #pragma unroll
            for (int i = 0; i < 4; ++i)
                af[i] = __builtin_bit_cast(bf16x8,
                    *(const s16x8*)(&Als[cur][(wm * 64 + i * 16 + l16) * 64 + csw8]));
            #pragma unroll
            for (int j = 0; j < 2; ++j)
                bf[j] = __builtin_bit_cast(bf16x8,
                    *(const s16x8*)(&Bls[cur][(wn * 32 + j * 16 + l16) * 64 + csw8]));
            #pragma unroll
            for (int i = 0; i < 4; ++i)
                #pragma unroll
                for (int j = 0; j < 2; ++j)
                    acc[i][j] = __builtin_amdgcn_mfma_f32_16x16x32_bf16(
                        af[i], bf[j], acc[i][j], 0, 0, 0);
        }
        if (ks < 3)
            __builtin_amdgcn_s_barrier(); // reads of cur done before re-stage
    }

    // epilogue 1: H write (C/D col=l16, row=quad*4+reg)
    int gcol0 = bc * 128 + wn * 32;
    int t   = gcol0 >> 8;
    int ch0 = gcol0 & 255;
    u16* Ht = H + (size_t)t * GAT_N * GAT_D;
    int rowb = br * 128 + wm * 64 + quad * 4;
    #pragma unroll
    for (int i = 0; i < 4; ++i) {
        #pragma unroll
        for (int j = 0; j < 2; ++j) {
            int ch = ch0 + j * 16 + l16;
            #pragma unroll
            for (int r = 0; r < 4; ++r) {
                int row = rowb + i * 16 + r;
                if (row < GAT_N) Ht[(size_t)row * GAT_D + ch] = f2bf(acc[i][j][r]);
            }
        }
    }

    // epilogue 2: attn dot partials; 16-lane DPP reduce then atomicAdd into
    // the per-layer accumulator (replaces part arrays + gat_sum).
    float asv[2], adv[2];
    #pragma unroll
    for (int j = 0; j < 2; ++j) {
        int ch = ch0 + j * 16 + l16;
        asv[j] = as_in[t * GAT_D + ch];
        adv[j] = ad_in[t * GAT_D + ch];
    }
    #pragma unroll
    for (int i = 0; i < 4; ++i) {
        float ps[4] = {}, pd[4] = {};
        #pragma unroll
        for (int j = 0; j < 2; ++j) {
            f32x4 a = acc[i][j];
            #pragma unroll
            for (int r = 0; r < 4; ++r) {
                ps[r] += a[r] * asv[j];
                pd[r] += a[r] * adv[j];
            }
        }
        #pragma unroll
        for (int r = 0; r < 4; ++r) {
            ps[r] = sum16(ps[r]);
            pd[r] = sum16(pd[r]);
        }
        if (l16 == 0) {
            int row = rowb + i * 16;
            #pragma unroll
            for (int r = 0; r < 4; ++r) {
                if (row + r < GAT_N) {
                    atomicAdd(&a_s[t * GAT_N + row + r], ps[r]);
                    atomicAdd(&a_d[t * GAT_N + row + r], pd[r]);
                }
            }
        }
    }
}

// ================= gather: wave-per-edge readlane + issue-early pipeline ====
// AT ROOFLINE (r7): CU-side demand 384 MB H reads + 25 MB writes / 61 us =
// 6.7 TB/s >= 6.3 TB/s achievable. Per-edge 512 B is compulsory. r10 slab
// form (deg + psrc2, tj from row id). Compute path untouched.
__global__ __launch_bounds__(64) void gat_gather(
    const u32* __restrict__ deg, const int* __restrict__ psrc2,
    const float* __restrict__ a_src, const float* __restrict__ a_dst,
    const u16* __restrict__ Hfb, const float* __restrict__ bias3,
    const float* __restrict__ Wh, const float* __restrict__ bh,
    int layer, u16* __restrict__ x2b, float* __restrict__ out)
{
    int n = blockIdx.x;
    int lane = threadIdx.x;

    u32 dv = deg[n];
    int dtot = (dv > 64u) ? 64 : (int)dv;            // clamp (unreachable)

    int  j     = lane;
    bool valid = j < dtot;
    int  rs    = valid ? psrc2[(size_t)n * 64 + j] : 0;
    int  tj    = (rs >= GAT_N) + (rs >= 2 * GAT_N);  // type from row id

    float as   = a_src[rs];                          // 600 KB array: L2-hit
    float adn  = a_dst[tj * GAT_N + n];

    const u16* Hl = Hfb + lane * 4;                  // lane's 8 B column slot
    u32x2 w[8];
    #pragma unroll
    for (int u = 0; u < 8; ++u) {
        int rv = __builtin_amdgcn_readlane(rs, u);   // SGPR broadcast
        w[u] = *(const u32x2*)(Hl + (size_t)rv * GAT_D);
    }

    float e = as + adn;
    e = (e > 0.f) ? e : GAT_SLOPE * e;
    float ex = valid ? __expf(e) : 0.f;

    float s0 = (tj == 0) ? ex : 0.f;
    float s1 = (tj == 1) ? ex : 0.f;
    float s2 = (tj == 2) ? ex : 0.f;
    s0 = sum16(s0); s1 = sum16(s1); s2 = sum16(s2);
    #pragma unroll
    for (int d = 16; d < 64; d <<= 1) {
        s0 += __shfl_xor(s0, d);
        s1 += __shfl_xor(s1, d);
        s2 += __shfl_xor(s2, d);
    }
    float den = (tj == 0) ? s0 : ((tj == 1) ? s1 : s2);
    float alv = valid ? ex / den : 0.f;              // this lane's alpha
    int av = __builtin_bit_cast(int, alv);

    float r[4] = {};
    int dpad = (dtot + 7) & ~7;
    for (int k0 = 0; ; k0 += 8) {
        float al[8]; u32x2 wc[8];
        #pragma unroll
        for (int u = 0; u < 8; ++u) {
            wc[u] = w[u];                            // SSA rename, not a copy
            al[u] = __builtin_bit_cast(float,
                        __builtin_amdgcn_readlane(av, k0 + u));
        }
        bool more = (k0 + 8 < dpad);
        if (more) {
            #pragma unroll
            for (int u = 0; u < 8; ++u) {
                int rv = __builtin_amdgcn_readlane(rs, k0 + 8 + u);
                w[u] = *(const u32x2*)(Hl + (size_t)rv * GAT_D);
            }
        }
        #pragma unroll
        for (int u = 0; u < 8; ++u) {
            r[0] += al[u] * lo16(wc[u].x);
            r[1] += al[u] * hi16(wc[u].x);
            r[2] += al[u] * lo16(wc[u].y);
            r[3] += al[u] * hi16(wc[u].y);
        }
        if (!more) break;
    }

    int c0 = lane * 4;
    const float* b3 = bias3 + layer * GAT_D;
    float v[4];
    #pragma unroll
    for (int i = 0; i < 4; ++i) v[i] = fmaxf(r[i] + b3[c0 + i], 0.f);

    if (layer == 0) {
        u16 pk[4];
        #pragma unroll
        for (int i = 0; i < 4; ++i) pk[i] = f2bf(v[i]);
        *(ushort4*)(x2b + (size_t)n * GAT_D + c0) = *(ushort4*)pk;
    } else {
        float wsum = 0.f;
        #pragma unroll
        for (int i = 0; i < 4; ++i) wsum += v[i] * Wh[c0 + i];
        wsum = sum16(wsum);
        wsum += __shfl_xor(wsum, 16);
        wsum += __shfl_xor(wsum, 32);
        if (lane == 0) out[n] = 1.0f / (1.0f + __expf(-(wsum + bh[0])));
    }
}

// retain harness-expected symbol
__global__ void PyGTypeSpecificGAT_80075370266775_kernel() {}

extern "C" void kernel_launch(void* const* d_in, const int* in_sizes, int n_in,
                              void* d_out, int out_size, void* d_ws, size_t ws_size,
                              hipStream_t stream)
{
    (void)in_sizes; (void)n_in; (void)out_size; (void)ws_size;
    const float* z   = (const float*)d_in[0];
    const int*   ei  = (const int*)d_in[1];
    const float* W1  = (const float*)d_in[2];
    const float* as1 = (const float*)d_in[3];
    const float* ad1 = (const float*)d_in[4];
    const float* b1  = (const float*)d_in[5];
    const float* W2  = (const float*)d_in[6];
    const float* as2 = (const float*)d_in[7];
    const float* ad2 = (const float*)d_in[8];
    const float* b2  = (const float*)d_in[9];
    const float* Wh  = (const float*)d_in[10];
    const float* bh  = (const float*)d_in[11];
    float* out = (float*)d_out;

    // ---- workspace (~146 MB; >=156 MB proven). zb/x2b must not be last
    // (gemm staging over-reads <=24 KB past row 50000). Zero-region
    // [deg | a0s | a0d | a1s | a1d] is contiguous -> ONE memset.
    char* p = (char*)d_ws;
    u16*  Hfb  = (u16*)p;  p += (size_t)GAT_T * GAT_N * GAT_D * 2;  // 76.8 MB
    u16*  x2b  = (u16*)p;  p += (size_t)GAT_N * GAT_D * 2;          // 25.6 MB
    u16*  zb   = (u16*)p;  p += (size_t)GAT_N * GAT_D * 2;          // 25.6 MB
    char* zero_base = p;
    u32*  deg  = (u32*)p;  p += (size_t)GAT_N * 4;                  // 0.2 MB
    float* a0s = (float*)p; p += (size_t)GAT_B * 4;                 // 0.6 MB
    float* a0d = (float*)p; p += (size_t)GAT_B * 4;                 // 0.6 MB
    float* a1s = (float*)p; p += (size_t)GAT_B * 4;                 // 0.6 MB
    float* a1d = (float*)p; p += (size_t)GAT_B * 4;                 // 0.6 MB
    size_t zbytes = (size_t)(p - zero_base);
    int*  psrc2 = (int*)p; p += (size_t)GAT_N * 64 * 4;             // 12.8 MB
    u16*  WT1b = (u16*)p;  p += (size_t)GAT_COLS * GAT_D * 2;
    u16*  WT2b = (u16*)p;  p += (size_t)GAT_COLS * GAT_D * 2;
    float* bias3 = (float*)p; p += 2 * GAT_D * 4;

    const int PREP_BLKS = (GAT_N * GAT_D / 4 + 255) / 256;  // 12500

    hipMemsetAsync(zero_base, 0, zbytes, stream);
    gat_prep<<<PREP_BLKS, 256, 0, stream>>>(W1, W2, z, b1, b2, ei,
                                            WT1b, WT2b, zb, deg, psrc2,
                                            bias3);

    // 49 slab-groups of 8 x 6 col tiles = 2352 blocks (6 tail blocks idle)
    const int GEMM_BLKS = 49 * 48;

    for (int layer = 0; layer < 2; ++layer) {
        const u16*   A   = (layer == 0) ? zb   : x2b;
        const u16*   WTb = (layer == 0) ? WT1b : WT2b;
        const float* as_ = (layer == 0) ? as1  : as2;
        const float* ad_ = (layer == 0) ? ad1  : ad2;
        float* aS = (layer == 0) ? a0s : a1s;
        float* aD = (layer == 0) ? a0d : a1d;

        gat_gemm<<<GEMM_BLKS, 512, 0, stream>>>(A, WTb, Hfb, as_, ad_,
                                                aS, aD);
        gat_gather<<<GAT_N, 64, 0, stream>>>(deg, psrc2, aS, aD,
                                             Hfb, bias3, Wh, bh,
                                             layer, x2b, out);
    }
}

// Round 12
// 355.135 us; speedup vs baseline: 1.0738x; 1.0738x over previous
//
#include <hip/hip_runtime.h>

#define GAT_N 50000
#define GAT_D 256
#define GAT_T 3
#define GAT_E 250000
#define GAT_B (GAT_T*GAT_N)      // 150000 (node,type) buckets
#define GAT_TOTE (GAT_T*GAT_E)   // 750000 edges total
#define GAT_COLS (GAT_T*GAT_D)   // 768 fused output columns
#define GAT_SLOPE 0.2f

typedef unsigned short u16;
typedef unsigned int u32;
typedef __attribute__((ext_vector_type(8))) short s16x8;     // raw bf16 storage
typedef __attribute__((ext_vector_type(8))) __bf16 bf16x8;   // MFMA operand
typedef __attribute__((ext_vector_type(4))) float f32x4;
typedef __attribute__((ext_vector_type(2))) u32 u32x2;

__device__ __forceinline__ u16 f2bf(float f) {
    u32 x = __builtin_bit_cast(u32, f);
    u32 r = (x + 0x7fffu + ((x >> 16) & 1u)) >> 16;   // RNE
    return (u16)r;
}
__device__ __forceinline__ float lo16(u32 w) {
    return __builtin_bit_cast(float, w << 16);
}
__device__ __forceinline__ float hi16(u32 w) {
    return __builtin_bit_cast(float, w & 0xffff0000u);
}

// ---- DPP butterfly adds (VALU pipe, NOT ds_swizzle/LDS pipe) --------------
template<int CTRL>
__device__ __forceinline__ float dppadd(float x) {
    int y = __builtin_amdgcn_update_dpp(0, __builtin_bit_cast(int, x),
                                        CTRL, 0xf, 0xf, true);
    return x + __builtin_bit_cast(float, y);
}
__device__ __forceinline__ float sum16(float x) {   // reduce within 16 lanes
    x = dppadd<0xB1>(x);
    x = dppadd<0x4E>(x);
    x = dppadd<0x141>(x);
    x = dppadd<0x140>(x);
    return x;
}

// ---- fused prep + scatter (r11 fusion KEPT; r12 reverts only the gemm
// atomic epilogue). prep: W transpose (coalesced OUT), z->bf16, bias3.
// scatter: fixed 64-slot slab per dst, atomicAdd(&deg[dst]); deg zeroed by
// the up-front memset (same stream, ordered).
__global__ void gat_prep(const float* __restrict__ W1, const float* __restrict__ W2,
                         const float* __restrict__ z, const float* __restrict__ b1,
                         const float* __restrict__ b2, const int* __restrict__ ei,
                         u16* __restrict__ WT1b, u16* __restrict__ WT2b,
                         u16* __restrict__ zb, u32* __restrict__ deg,
                         int* __restrict__ psrc2, float* __restrict__ bias3)
{
    int idx = blockIdx.x * 256 + threadIdx.x;
    if (idx < GAT_T * GAT_D * GAT_D) {               // 196608 OUTPUT slots
        int t = idx >> 16, r = idx & 65535;
        int h = r >> 8, d = r & 255;                 // out = [t][h][d]
        WT1b[idx] = f2bf(W1[t * 65536 + d * 256 + h]);
        WT2b[idx] = f2bf(W2[t * 65536 + d * 256 + h]);
    }
    if (idx < 2 * GAT_D) {
        const float* bb = (idx < GAT_D) ? b1 : b2;
        int c = idx & 255;
        bias3[idx] = bb[c] + bb[GAT_D + c] + bb[2 * GAT_D + c];
    }
    if (idx < GAT_TOTE) {                            // fused scatter
        int t = idx / GAT_E;
        int e = idx - t * GAT_E;
        int src = ei[t * 2 * GAT_E + e];
        int dst = ei[t * 2 * GAT_E + GAT_E + e];
        u32 slot = atomicAdd(&deg[dst], 1u);
        if (slot < 64u)                              // safety clamp
            psrc2[(size_t)dst * 64 + slot] = t * GAT_N + src;
    }
    if (idx < GAT_N * GAT_D / 4) {
        f32x4 v = ((const f32x4*)z)[idx];
        ushort4 pk;
        pk.x = f2bf(v.x); pk.y = f2bf(v.y); pk.z = f2bf(v.z); pk.w = f2bf(v.w);
        ((ushort4*)zb)[idx] = pk;
    }
}

// ================= LDS-staged MFMA GEMM (XOR-swizzled) + partial attn dots ==
// r7/r10 config (best measured): 128x128 tile, 512-thread/8-wave blocks,
// 64 KB dbuf LDS, counted vmcnt, XCD grid swizzle, DPP epilogue, partials
// to part arrays (plain coalesced stores). r12: REVERTED r11's atomicAdd
// epilogue -- it inflated WRITE_SIZE 79.7->112.5 MB (fp32 atomic RMW
// 32B-sector write-back amplification) and cost gemm +5 us/dispatch.
__global__ __launch_bounds__(512, 4) void gat_gemm(
    const u16* __restrict__ A, const u16* __restrict__ WTb,
    u16* __restrict__ H, const float* __restrict__ as_in,
    const float* __restrict__ ad_in, float* __restrict__ part_src,
    float* __restrict__ part_dst)
{
    // decode XCD-grouped swizzle
    int lin = blockIdx.x;
    int g   = lin / 48;
    int rem = lin - g * 48;
    int bc  = rem >> 3;                 // col tile 0..5
    int br  = (g << 3) + (rem & 7);     // row slab 0..390
    if (br >= 391) return;

    __shared__ u16 Als[2][128 * 64];   // 2 x 16 KB
    __shared__ u16 Bls[2][128 * 64];   // 2 x 16 KB
    int tid  = threadIdx.x;
    int wave = tid >> 6, lane = tid & 63;
    int quad = lane >> 4, l16 = lane & 15;
    int wm = wave & 1, wn = wave >> 1;       // wm: row half, wn: col quarter
    int lrow = lane >> 3;                    // 0..7
    int swz  = ((lane & 7) ^ lrow) * 8;      // swizzled k-offset (u16)

    size_t arow0 = (size_t)br * 128;
    size_t brow0 = (size_t)bc * 128;

    auto STAGE = [&](int buf, int ks) {
        int k0 = ks * 64;
        #pragma unroll
        for (int r = 0; r < 2; ++r) {
            int srow = wave * 16 + r * 8 + lrow;
            const u16* gA = A   + (arow0 + srow) * GAT_D + k0 + swz;
            const u16* gB = WTb + (brow0 + srow) * GAT_D + k0 + swz;
            u16* lA = &Als[buf][wave * 1024 + r * 512];   // wave-uniform dest
            u16* lB = &Bls[buf][wave * 1024 + r * 512];
#if defined(__has_builtin) && __has_builtin(__builtin_amdgcn_global_load_lds)
            __builtin_amdgcn_global_load_lds(
                (const __attribute__((address_space(1))) void*)gA,
                (__attribute__((address_space(3))) void*)lA, 16, 0, 0);
            __builtin_amdgcn_global_load_lds(
                (const __attribute__((address_space(1))) void*)gB,
                (__attribute__((address_space(3))) void*)lB, 16, 0, 0);
#else
            *(s16x8*)(lA + lane * 8) = *(const s16x8*)gA;
            *(s16x8*)(lB + lane * 8) = *(const s16x8*)gB;
#endif
        }
    };

    f32x4 acc[4][2] = {};

    STAGE(0, 0);
    #pragma unroll
    for (int ks = 0; ks < 4; ++ks) {
        int cur = ks & 1;
        if (ks < 3) {
            STAGE(cur ^ 1, ks + 1);
            asm volatile("s_waitcnt vmcnt(4)" ::: "memory");
        } else {
            asm volatile("s_waitcnt vmcnt(0)" ::: "memory");
        }
        __builtin_amdgcn_s_barrier();     // all waves' stage of cur complete

        #pragma unroll
        for (int kk = 0; kk < 2; ++kk) {
            int csw8 = ((kk * 4 + quad) ^ (l16 & 7)) * 8;   // row&7 == l16&7
            bf16x8 af[4], bf[2];
            #pragma unroll
            for (int i = 0; i < 4; ++i)
                af[i] = __builtin_bit_cast(bf16x8,
                    *(const s16x8*)(&Als[cur][(wm * 64 + i * 16 + l16) * 64 + csw8]));
            #pragma unroll
            for (int j = 0; j < 2; ++j)
                bf[j] = __builtin_bit_cast(bf16x8,
                    *(const s16x8*)(&Bls[cur][(wn * 32 + j * 16 + l16) * 64 + csw8]));
            #pragma unroll
            for (int i = 0; i < 4; ++i)
                #pragma unroll
                for (int j = 0; j < 2; ++j)
                    acc[i][j] = __builtin_amdgcn_mfma_f32_16x16x32_bf16(
                        af[i], bf[j], acc[i][j], 0, 0, 0);
        }
        if (ks < 3)
            __builtin_amdgcn_s_barrier(); // reads of cur done before re-stage
    }

    // epilogue 1: H write (C/D col=l16, row=quad*4+reg)
    int gcol0 = bc * 128 + wn * 32;
    int t   = gcol0 >> 8;
    int ch0 = gcol0 & 255;
    int c32 = bc * 4 + wn;                       // 0..23 (type = c32>>3)
    u16* Ht = H + (size_t)t * GAT_N * GAT_D;
    int rowb = br * 128 + wm * 64 + quad * 4;
    #pragma unroll
    for (int i = 0; i < 4; ++i) {
        #pragma unroll
        for (int j = 0; j < 2; ++j) {
            int ch = ch0 + j * 16 + l16;
            #pragma unroll
            for (int r = 0; r < 4; ++r) {
                int row = rowb + i * 16 + r;
                if (row < GAT_N) Ht[(size_t)row * GAT_D + ch] = f2bf(acc[i][j][r]);
            }
        }
    }

    // epilogue 2: attn dot partials; 16-lane reduction via DPP (VALU pipe).
    float asv[2], adv[2];
    #pragma unroll
    for (int j = 0; j < 2; ++j) {
        int ch = ch0 + j * 16 + l16;
        asv[j] = as_in[t * GAT_D + ch];
        adv[j] = ad_in[t * GAT_D + ch];
    }
    #pragma unroll
    for (int i = 0; i < 4; ++i) {
        float ps[4] = {}, pd[4] = {};
        #pragma unroll
        for (int j = 0; j < 2; ++j) {
            f32x4 a = acc[i][j];
            #pragma unroll
            for (int r = 0; r < 4; ++r) {
                ps[r] += a[r] * asv[j];
                pd[r] += a[r] * adv[j];
            }
        }
        #pragma unroll
        for (int r = 0; r < 4; ++r) {
            ps[r] = sum16(ps[r]);
            pd[r] = sum16(pd[r]);
        }
        if (l16 == 0) {
            int row = rowb + i * 16;
            #pragma unroll
            for (int r = 0; r < 4; ++r) {
                if (row + r < GAT_N) {
                    part_src[(size_t)c32 * GAT_N + row + r] = ps[r];
                    part_dst[(size_t)c32 * GAT_N + row + r] = pd[r];
                }
            }
        }
    }
}

// ---- reduce 8 col-chunk partials -> a_src/a_dst[t*N+n] (coalesced) --------
__global__ void gat_sum(const float* __restrict__ part_src,
                        const float* __restrict__ part_dst,
                        float* __restrict__ a_src, float* __restrict__ a_dst)
{
    int idx = blockIdx.x * 256 + threadIdx.x;        // [0, 3N)
    if (idx >= GAT_B) return;
    int t = idx / GAT_N;
    int n = idx - t * GAT_N;
    const float* ps = part_src + (size_t)8 * t * GAT_N;
    const float* pd = part_dst + (size_t)8 * t * GAT_N;
    float s = 0.f, d = 0.f;
    #pragma unroll
    for (int c = 0; c < 8; ++c) {
        s += ps[(size_t)c * GAT_N + n];
        d += pd[(size_t)c * GAT_N + n];
    }
    a_src[idx] = s;
    a_dst[idx] = d;
}

// ================= gather: wave-per-edge readlane + issue-early pipeline ====
// AT ROOFLINE (r7): CU-side demand 384 MB H reads + 25 MB writes / 61 us =
// 6.7 TB/s >= 6.3 TB/s achievable. Per-edge 512 B is compulsory. r10 slab
// form (deg + psrc2, tj from row id). Compute path untouched.
__global__ __launch_bounds__(64) void gat_gather(
    const u32* __restrict__ deg, const int* __restrict__ psrc2,
    const float* __restrict__ a_src, const float* __restrict__ a_dst,
    const u16* __restrict__ Hfb, const float* __restrict__ bias3,
    const float* __restrict__ Wh, const float* __restrict__ bh,
    int layer, u16* __restrict__ x2b, float* __restrict__ out)
{
    int n = blockIdx.x;
    int lane = threadIdx.x;

    u32 dv = deg[n];
    int dtot = (dv > 64u) ? 64 : (int)dv;            // clamp (unreachable)

    int  j     = lane;
    bool valid = j < dtot;
    int  rs    = valid ? psrc2[(size_t)n * 64 + j] : 0;
    int  tj    = (rs >= GAT_N) + (rs >= 2 * GAT_N);  // type from row id

    float as   = a_src[rs];                          // 600 KB array: L2-hit
    float adn  = a_dst[tj * GAT_N + n];

    const u16* Hl = Hfb + lane * 4;                  // lane's 8 B column slot
    u32x2 w[8];
    #pragma unroll
    for (int u = 0; u < 8; ++u) {
        int rv = __builtin_amdgcn_readlane(rs, u);   // SGPR broadcast
        w[u] = *(const u32x2*)(Hl + (size_t)rv * GAT_D);
    }

    float e = as + adn;
    e = (e > 0.f) ? e : GAT_SLOPE * e;
    float ex = valid ? __expf(e) : 0.f;

    float s0 = (tj == 0) ? ex : 0.f;
    float s1 = (tj == 1) ? ex : 0.f;
    float s2 = (tj == 2) ? ex : 0.f;
    s0 = sum16(s0); s1 = sum16(s1); s2 = sum16(s2);
    #pragma unroll
    for (int d = 16; d < 64; d <<= 1) {
        s0 += __shfl_xor(s0, d);
        s1 += __shfl_xor(s1, d);
        s2 += __shfl_xor(s2, d);
    }
    float den = (tj == 0) ? s0 : ((tj == 1) ? s1 : s2);
    float alv = valid ? ex / den : 0.f;              // this lane's alpha
    int av = __builtin_bit_cast(int, alv);

    float r[4] = {};
    int dpad = (dtot + 7) & ~7;
    for (int k0 = 0; ; k0 += 8) {
        float al[8]; u32x2 wc[8];
        #pragma unroll
        for (int u = 0; u < 8; ++u) {
            wc[u] = w[u];                            // SSA rename, not a copy
            al[u] = __builtin_bit_cast(float,
                        __builtin_amdgcn_readlane(av, k0 + u));
        }
        bool more = (k0 + 8 < dpad);
        if (more) {
            #pragma unroll
            for (int u = 0; u < 8; ++u) {
                int rv = __builtin_amdgcn_readlane(rs, k0 + 8 + u);
                w[u] = *(const u32x2*)(Hl + (size_t)rv * GAT_D);
            }
        }
        #pragma unroll
        for (int u = 0; u < 8; ++u) {
            r[0] += al[u] * lo16(wc[u].x);
            r[1] += al[u] * hi16(wc[u].x);
            r[2] += al[u] * lo16(wc[u].y);
            r[3] += al[u] * hi16(wc[u].y);
        }
        if (!more) break;
    }

    int c0 = lane * 4;
    const float* b3 = bias3 + layer * GAT_D;
    float v[4];
    #pragma unroll
    for (int i = 0; i < 4; ++i) v[i] = fmaxf(r[i] + b3[c0 + i], 0.f);

    if (layer == 0) {
        u16 pk[4];
        #pragma unroll
        for (int i = 0; i < 4; ++i) pk[i] = f2bf(v[i]);
        *(ushort4*)(x2b + (size_t)n * GAT_D + c0) = *(ushort4*)pk;
    } else {
        float wsum = 0.f;
        #pragma unroll
        for (int i = 0; i < 4; ++i) wsum += v[i] * Wh[c0 + i];
        wsum = sum16(wsum);
        wsum += __shfl_xor(wsum, 16);
        wsum += __shfl_xor(wsum, 32);
        if (lane == 0) out[n] = 1.0f / (1.0f + __expf(-(wsum + bh[0])));
    }
}

// retain harness-expected symbol
__global__ void PyGTypeSpecificGAT_80075370266775_kernel() {}

extern "C" void kernel_launch(void* const* d_in, const int* in_sizes, int n_in,
                              void* d_out, int out_size, void* d_ws, size_t ws_size,
                              hipStream_t stream)
{
    (void)in_sizes; (void)n_in; (void)out_size; (void)ws_size;
    const float* z   = (const float*)d_in[0];
    const int*   ei  = (const int*)d_in[1];
    const float* W1  = (const float*)d_in[2];
    const float* as1 = (const float*)d_in[3];
    const float* ad1 = (const float*)d_in[4];
    const float* b1  = (const float*)d_in[5];
    const float* W2  = (const float*)d_in[6];
    const float* as2 = (const float*)d_in[7];
    const float* ad2 = (const float*)d_in[8];
    const float* b2  = (const float*)d_in[9];
    const float* Wh  = (const float*)d_in[10];
    const float* bh  = (const float*)d_in[11];
    float* out = (float*)d_out;

    // ---- workspace (~153 MB; >=156 MB proven). zb/x2b must not be last
    // (gemm staging over-reads <=24 KB past row 50000).
    char* p = (char*)d_ws;
    u16*  Hfb  = (u16*)p;  p += (size_t)GAT_T * GAT_N * GAT_D * 2;  // 76.8 MB
    u16*  x2b  = (u16*)p;  p += (size_t)GAT_N * GAT_D * 2;          // 25.6 MB
    u16*  zb   = (u16*)p;  p += (size_t)GAT_N * GAT_D * 2;          // 25.6 MB
    float* part_src = (float*)p; p += (size_t)24 * GAT_N * 4;       // 4.8 MB
    float* part_dst = (float*)p; p += (size_t)24 * GAT_N * 4;       // 4.8 MB
    float* a_src = (float*)p; p += (size_t)GAT_B * 4;               // 0.6 MB
    float* a_dst = (float*)p; p += (size_t)GAT_B * 4;               // 0.6 MB
    u32*  deg  = (u32*)p;  p += (size_t)GAT_N * 4;                  // 0.2 MB
    int*  psrc2 = (int*)p; p += (size_t)GAT_N * 64 * 4;             // 12.8 MB
    u16*  WT1b = (u16*)p;  p += (size_t)GAT_COLS * GAT_D * 2;
    u16*  WT2b = (u16*)p;  p += (size_t)GAT_COLS * GAT_D * 2;
    float* bias3 = (float*)p; p += 2 * GAT_D * 4;

    const int BUCK_BLKS = (GAT_B + 255) / 256;              // 586
    const int PREP_BLKS = (GAT_N * GAT_D / 4 + 255) / 256;  // 12500

    hipMemsetAsync(deg, 0, (size_t)GAT_N * 4, stream);
    gat_prep<<<PREP_BLKS, 256, 0, stream>>>(W1, W2, z, b1, b2, ei,
                                            WT1b, WT2b, zb, deg, psrc2,
                                            bias3);

    // 49 slab-groups of 8 x 6 col tiles = 2352 blocks (6 tail blocks idle)
    const int GEMM_BLKS = 49 * 48;

    for (int layer = 0; layer < 2; ++layer) {
        const u16*   A   = (layer == 0) ? zb   : x2b;
        const u16*   WTb = (layer == 0) ? WT1b : WT2b;
        const float* as_ = (layer == 0) ? as1  : as2;
        const float* ad_ = (layer == 0) ? ad1  : ad2;

        gat_gemm<<<GEMM_BLKS, 512, 0, stream>>>(A, WTb, Hfb, as_, ad_,
                                                part_src, part_dst);
        gat_sum<<<BUCK_BLKS, 256, 0, stream>>>(part_src, part_dst,
                                               a_src, a_dst);
        gat_gather<<<GAT_N, 64, 0, stream>>>(deg, psrc2, a_src, a_dst,
                                             Hfb, bias3, Wh, bh,
                                             layer, x2b, out);
    }
}